// Round 10
// baseline (257.594 us; speedup 1.0000x reference)
//
#include <hip/hip_runtime.h>
#include <hip/hip_bf16.h>

#define IN_DIM    1024
#define HEAD_DIM  64
#define NUM_HEADS 16
#define SEQ       4096

// 1/sqrt(64) * log2(e), folded into Q (fp32, pre-bf16-cast). Softmax computed
// with exp2 (v_exp_f32 IS 2^x) -> no per-element ln2 prescale mul in attn.
#define QSCALE 0.18033688011112042f

typedef __bf16 bf16;
typedef __attribute__((ext_vector_type(4))) __bf16 bf16x4;
typedef __attribute__((ext_vector_type(8))) __bf16 bf16x8;
typedef __attribute__((ext_vector_type(4))) float floatx4;
typedef __attribute__((ext_vector_type(16))) float floatx16;
typedef __attribute__((ext_vector_type(4))) unsigned uint32x4;

__device__ __forceinline__ void async16(bf16* lds, const bf16* g) {
    __builtin_amdgcn_global_load_lds(
        (const __attribute__((address_space(1))) unsigned int*)g,
        (__attribute__((address_space(3))) unsigned int*)lds, 16, 0, 0);
}

// TRANS (v_exp_f32) -> VALU consumer needs wait states; the hazard
// recognizer may not protect an inline-asm consumer.  s_nop 1 = 2 waits.
__device__ __forceinline__ unsigned cvtpk_bf16(float lo, float hi) {
    unsigned r;
    asm volatile("s_nop 1\n\tv_cvt_pk_bf16_f32 %0, %1, %2"
                 : "=v"(r) : "v"(lo), "v"(hi));
    return r;
}

// v_permlane32_swap_b32 vdst, vsrc (CDNA4): vdst[32:63] <-> vsrc[0:31].
// VALU-write -> permlane-read needs wait states; invisible across adjacent
// asm blocks.  s_nop 3 = 4 waits, scheduling-independent protection.
__device__ __forceinline__ void permswap(unsigned& a, unsigned& b) {
    asm volatile("s_nop 3\n\tv_permlane32_swap_b32 %0, %1" : "+v"(a), "+v"(b));
}

// p = exp2(s); pack PV A-frags in-register (cvt_pk + permlane32_swap; swap
// direction vdst.hi <-> vsrc.lo, arg order verified R2).  S0 covers t-slots
// 0,1; S1 slots 2,3; slot sl uses regs 8*(sl&1)..+7.
#define PACK(PA, S0, S1)                                                       \
    _Pragma("unroll")                                                          \
    for (int sl = 0; sl < 4; ++sl) {                                           \
        const floatx16 sv = (sl < 2) ? (S0) : (S1);                            \
        const int rb = 8 * (sl & 1);                                           \
        float p0 = __builtin_amdgcn_exp2f(sv[rb + 0]);                         \
        float p1 = __builtin_amdgcn_exp2f(sv[rb + 1]);                         \
        float p2 = __builtin_amdgcn_exp2f(sv[rb + 2]);                         \
        float p3 = __builtin_amdgcn_exp2f(sv[rb + 3]);                         \
        float p4 = __builtin_amdgcn_exp2f(sv[rb + 4]);                         \
        float p5 = __builtin_amdgcn_exp2f(sv[rb + 5]);                         \
        float p6 = __builtin_amdgcn_exp2f(sv[rb + 6]);                         \
        float p7 = __builtin_amdgcn_exp2f(sv[rb + 7]);                         \
        unsigned u0 = cvtpk_bf16(p0, p1);                                      \
        unsigned u1 = cvtpk_bf16(p2, p3);                                      \
        unsigned u2 = cvtpk_bf16(p4, p5);                                      \
        unsigned u3 = cvtpk_bf16(p6, p7);                                      \
        permswap(u0, u2);                                                      \
        permswap(u1, u3);                                                      \
        uint32x4 w;                                                            \
        w[0] = u0; w[1] = u1; w[2] = u2; w[3] = u3;                            \
        (PA)[sl] = __builtin_bit_cast(bf16x8, w);                              \
    }

// ---------------------------------------------------------------------------
// ws layout: hb @0 (8MB) | Wt @8MB (6MB, n-major) | Qb @14MB | Kb @22MB | Vt @30MB
// ---------------------------------------------------------------------------

__global__ void mha_conv_h(const float* __restrict__ h, bf16* __restrict__ hb) {
    int i = blockIdx.x * blockDim.x + threadIdx.x;
    float4 v = ((const float4*)h)[i];
    bf16x4 r;
    r[0] = (bf16)v.x; r[1] = (bf16)v.y; r[2] = (bf16)v.z; r[3] = (bf16)v.w;
    ((bf16x4*)hb)[i] = r;
}

__global__ void mha_conv_wt(const float* __restrict__ Wq, const float* __restrict__ Wk,
                            const float* __restrict__ Wv, bf16* __restrict__ Wt) {
    __shared__ bf16 tile[64][65];
    const int mat = blockIdx.z;
    const float* W = (mat == 0) ? Wq : (mat == 1) ? Wk : Wv;
    const int k0 = blockIdx.y * 64, n0 = blockIdx.x * 64;
    const int tn = threadIdx.x & 63, tq = threadIdx.x >> 6;
#pragma unroll
    for (int i = 0; i < 16; ++i) {
        int kk = tq + i * 4;
        tile[kk][tn] = (bf16)W[(size_t)(k0 + kk) * 1024 + n0 + tn];
    }
    __syncthreads();
#pragma unroll
    for (int i = 0; i < 16; ++i) {
        int nn = tq + i * 4;
        Wt[((size_t)mat << 20) + (size_t)(n0 + nn) * 1024 + k0 + tn] = tile[tn][nn];
    }
}

// ---------------------------------------------------------------------------
// QKV GEMM, m97-style: 128x128 tile, BK=32, global_load_lds staging,
// XOR-swizzled chunks so frag ds_read_b128 lands 2-way (free).
// R0-R5 EXACT (verified ~90us on this shape).
// ---------------------------------------------------------------------------
__launch_bounds__(256)
__global__ void mha_qkv_gemm(const bf16* __restrict__ hb, const bf16* __restrict__ Wt,
                             const float* __restrict__ bq, const float* __restrict__ bk,
                             const float* __restrict__ bv,
                             bf16* __restrict__ Qb, bf16* __restrict__ Kb,
                             bf16* __restrict__ Vt) {
    __shared__ __align__(16) bf16 As[128 * 32];
    __shared__ __align__(16) bf16 Bs[128 * 32];

    const int lane = threadIdx.x & 63;
    const int wave = threadIdx.x >> 6;
    const int l16  = lane & 15;
    const int quad = lane >> 4;
    const int wm   = wave & 1;
    const int wn   = wave >> 1;

    const int m0  = blockIdx.x * 128;
    const int n0  = blockIdx.y * 128;
    const int mat = n0 >> 10;
    const int nc0 = n0 & 1023;

    const bf16* Wp = Wt + ((size_t)mat << 20);

    floatx4 acc[4][4] = {};
    const int swz = (l16 >> 1) & 3;

    for (int k0 = 0; k0 < IN_DIM; k0 += 32) {
#pragma unroll
        for (int r = 0; r < 2; ++r) {
            int g = wave * 128 + r * 64 + lane;
            int row = g >> 2, c = g & 3;
            int gc = c ^ ((row >> 1) & 3);
            bf16* ldsbase_a = As + (size_t)(wave * 128 + r * 64) * 8;
            bf16* ldsbase_b = Bs + (size_t)(wave * 128 + r * 64) * 8;
            async16(ldsbase_a, hb + (size_t)(m0 + row) * IN_DIM + k0 + gc * 8);
            async16(ldsbase_b, Wp + (size_t)(nc0 + row) * IN_DIM + k0 + gc * 8);
        }
        __syncthreads();

        bf16x8 af[4], bf[4];
#pragma unroll
        for (int mt = 0; mt < 4; ++mt)
            af[mt] = *(const bf16x8*)(As + (size_t)(wm * 64 + mt * 16 + l16) * 32
                                      + ((quad ^ swz) * 8));
#pragma unroll
        for (int nt = 0; nt < 4; ++nt)
            bf[nt] = *(const bf16x8*)(Bs + (size_t)(wn * 64 + nt * 16 + l16) * 32
                                      + ((quad ^ swz) * 8));
#pragma unroll
        for (int mt = 0; mt < 4; ++mt)
#pragma unroll
            for (int nt = 0; nt < 4; ++nt)
                acc[mt][nt] = __builtin_amdgcn_mfma_f32_16x16x32_bf16(af[mt], bf[nt],
                                                                      acc[mt][nt], 0, 0, 0);
        __syncthreads();
    }

    const float* bias = (mat == 0) ? bq : (mat == 1) ? bk : bv;
#pragma unroll
    for (int nt = 0; nt < 4; ++nt) {
        int nc = nc0 + wn * 64 + nt * 16 + l16;
        float bb = bias[nc];
        int head = nc >> 6, d = nc & 63;
#pragma unroll
        for (int mt = 0; mt < 4; ++mt)
#pragma unroll
            for (int r = 0; r < 4; ++r) {
                int srow = m0 + wm * 64 + mt * 16 + quad * 4 + r;
                float v = acc[mt][nt][r] + bb;
                if (mat == 0)
                    Qb[((size_t)head * SEQ + srow) * HEAD_DIM + d] = (bf16)(v * QSCALE);
                else if (mat == 1)
                    Kb[((size_t)head * SEQ + srow) * HEAD_DIM + d] = (bf16)v;
                else
                    Vt[((size_t)head * HEAD_DIM + d) * SEQ + srow] = (bf16)v;
            }
    }
}

// ---------------------------------------------------------------------------
// Attention v5c: 4 waves x 64 q-rows (256 q/block, 256 blocks = 1/CU).
// R8 failed at 1.35e-2 with DUAL interleaved PACK chains; R9 (s_nop probe)
// died to an infra abort (no in-kernel fault source found on audit).  v5c
// makes the hazard theory moot: the two q-tile pipelines are SERIALIZED
// (S-a, PACK-a, PV-a, S-b, PACK-b, PV-b) so each PACK sits between MFMA
// clusters exactly like the many-times-verified v4 schedule, and both asm
// helpers carry internal s_nop hazard padding (+volatile).  Also cuts peak
// VGPR ~50 (s0b/s1b never coexist with paa).
// Geometry rationale (R7 accounting): v4 was LDS-read-pipe bound -- 8 waves
// re-reading identical K/V frags.  4 waves x 2 q-tiles halves LDS reads per
// CU-iter (~1300 cyc) -> matrix pipe (~1280 cyc) becomes co-binding.
// Staging (2 chunks/thread), counted vmcnt ladder 8/4/0 (induction-proven),
// 3-buffer rotation, XCD-head swizzle: all identical to R8.
// ---------------------------------------------------------------------------
__launch_bounds__(256, 1)
__global__ void mha_attn(const bf16* __restrict__ Qb, const bf16* __restrict__ Kb,
                         const bf16* __restrict__ Vt, float* __restrict__ out) {
    __shared__ __align__(16) bf16 Ks[3][64 * 64];       // 24 KB
    __shared__ __align__(16) bf16 Vs[3][64 * 64];       // 24 KB (d-major V^T)

    const int lane = threadIdx.x & 63;
    const int wave = threadIdx.x >> 6;   // 0..3
    const int l31  = lane & 31;
    const int hi   = lane >> 5;

    // XCD-head swizzle: 256 blocks; XCD k (= bid%8) gets heads {2k, 2k+1}
    const int bid = blockIdx.x;
    const int hh  = 2 * (bid & 7) + ((bid >> 3) & 1);
    const int qx  = bid >> 4;
    const int q0  = qx * 256 + wave * 64;

    const bf16* Qh = Qb + (size_t)hh * SEQ * HEAD_DIM;
    const bf16* Kh = Kb + (size_t)hh * SEQ * HEAD_DIM;
    const bf16* Vh = Vt + (size_t)hh * HEAD_DIM * SEQ;

    // staging: 64x64 tile = 512 chunks of 16B; 256 threads stage 2 chunks.
    // chunk ci: row = ci>>3, src chunk = (ci&7)^(row&7); LDS dest linear at
    // ci*16B (wave-uniform base + lane*16B, as global_load_lds requires).
    const int ci0 = wave * 64 + lane;                     // 0..255 (rows 0..31)
    const int r0c = ci0 >> 3;
    const int sc0 = (ci0 & 7) ^ (r0c & 7);
    const int r1c = r0c + 32;                             // rows 32..63
    const int sc1 = sc0;                                  // (+256 keeps &7 bits)

    // Q fragments, two 32-q tiles: qf*[ks][e] = Q[q|l31][ks*16 + hi*8 + e]
    bf16x8 qfa[4], qfb[4];
#pragma unroll
    for (int ks = 0; ks < 4; ++ks) {
        qfa[ks] = *(const bf16x8*)(Qh + (size_t)(q0 + l31) * HEAD_DIM + ks * 16 + hi * 8);
        qfb[ks] = *(const bf16x8*)(Qh + (size_t)(q0 + 32 + l31) * HEAD_DIM + ks * 16 + hi * 8);
    }

    bf16x8 vone;
#pragma unroll
    for (int i = 0; i < 8; ++i) vone[i] = (bf16)1.0f;

    floatx16 o0a = {}, o1a = {}, ola = {};
    floatx16 o0b = {}, o1b = {}, olb = {};
    const int swz = l31 & 7;

    auto stageK = [&](int buf, int t0) {
        async16(&Ks[buf][wave * 512],        Kh + (size_t)(t0 + r0c) * HEAD_DIM + sc0 * 8);
        async16(&Ks[buf][2048 + wave * 512], Kh + (size_t)(t0 + r1c) * HEAD_DIM + sc1 * 8);
    };
    auto stageV = [&](int buf, int t0) {
        async16(&Vs[buf][wave * 512],        Vh + (size_t)r0c * SEQ + t0 + sc0 * 8);
        async16(&Vs[buf][2048 + wave * 512], Vh + (size_t)r1c * SEQ + t0 + sc1 * 8);
    };

    // prologue: stage tiles 0,1; one-time full drain (also drains qf loads so
    // the in-loop counted vmcnt sees ONLY staging DMAs).
    stageK(0, 0);  stageV(0, 0);
    stageK(1, 64); stageV(1, 64);
    asm volatile("s_waitcnt vmcnt(0)" ::: "memory");
    __builtin_amdgcn_s_barrier();

    int cur = 0;
    for (int t = 0; t < SEQ / 64; ++t) {
        int pre = cur + 2; if (pre >= 3) pre -= 3;
        if (t + 2 < SEQ / 64) {
            stageK(pre, (t + 2) * 64);
            stageV(pre, (t + 2) * 64);
        }
        if (t < SEQ / 64 - 2)       asm volatile("s_waitcnt vmcnt(8)" ::: "memory");
        else if (t == SEQ / 64 - 2) asm volatile("s_waitcnt vmcnt(4)" ::: "memory");
        else                        asm volatile("s_waitcnt vmcnt(0)" ::: "memory");
        __builtin_amdgcn_s_barrier();
        asm volatile("" ::: "memory");

        // K fragments (read ONCE, feed both q-tiles):
        bf16x8 kf[2][4];
#pragma unroll
        for (int tt = 0; tt < 2; ++tt)
#pragma unroll
            for (int ks = 0; ks < 4; ++ks)
                kf[tt][ks] = *(const bf16x8*)(&Ks[cur][(tt * 32 + l31) * 64
                                              + (((ks * 2 + hi) ^ swz) * 8)]);

        // V fragments (read ONCE): vf[dt][sl] = V[t=sl*16+hi*8..+8][d=dt*32+l31]
        bf16x8 vf[2][4];
#pragma unroll
        for (int dt = 0; dt < 2; ++dt)
#pragma unroll
            for (int sl = 0; sl < 4; ++sl)
                vf[dt][sl] = *(const bf16x8*)(&Vs[cur][(dt * 32 + l31) * 64
                                              + (((sl * 2 + hi) ^ swz) * 8)]);

        // ======== q-tile A: full pipeline (verified v4 schedule shape) ======
        floatx16 s0a = {}, s1a = {};
#pragma unroll
        for (int ks = 0; ks < 4; ++ks) {
            s0a = __builtin_amdgcn_mfma_f32_32x32x16_bf16(kf[0][ks], qfa[ks], s0a, 0, 0, 0);
            s1a = __builtin_amdgcn_mfma_f32_32x32x16_bf16(kf[1][ks], qfa[ks], s1a, 0, 0, 0);
        }
        bf16x8 paa[4];
        PACK(paa, s0a, s1a)
#pragma unroll
        for (int sl = 0; sl < 4; ++sl) {
            o0a = __builtin_amdgcn_mfma_f32_32x32x16_bf16(paa[sl], vf[0][sl], o0a, 0, 0, 0);
            o1a = __builtin_amdgcn_mfma_f32_32x32x16_bf16(paa[sl], vf[1][sl], o1a, 0, 0, 0);
            ola = __builtin_amdgcn_mfma_f32_32x32x16_bf16(paa[sl], vone,      ola, 0, 0, 0);
        }

        // ======== q-tile B: full pipeline ==================================
        floatx16 s0b = {}, s1b = {};
#pragma unroll
        for (int ks = 0; ks < 4; ++ks) {
            s0b = __builtin_amdgcn_mfma_f32_32x32x16_bf16(kf[0][ks], qfb[ks], s0b, 0, 0, 0);
            s1b = __builtin_amdgcn_mfma_f32_32x32x16_bf16(kf[1][ks], qfb[ks], s1b, 0, 0, 0);
        }
        bf16x8 pab[4];
        PACK(pab, s0b, s1b)
#pragma unroll
        for (int sl = 0; sl < 4; ++sl) {
            o0b = __builtin_amdgcn_mfma_f32_32x32x16_bf16(pab[sl], vf[0][sl], o0b, 0, 0, 0);
            o1b = __builtin_amdgcn_mfma_f32_32x32x16_bf16(pab[sl], vf[1][sl], o1b, 0, 0, 0);
            olb = __builtin_amdgcn_mfma_f32_32x32x16_bf16(pab[sl], vone,      olb, 0, 0, 0);
        }

        asm volatile("" ::: "memory");
        __builtin_amdgcn_s_barrier();      // reads of buf[cur] done before restage
        cur = cur + 1; if (cur == 3) cur = 0;
    }

    // epilogue: O rows q = q0 (+32 for tile b) + (r&3)+8*(r>>2)+4*hi
#pragma unroll
    for (int r = 0; r < 16; ++r) {
        const int qa = q0 + (r & 3) + 8 * (r >> 2) + 4 * hi;
        const float inva = 1.0f / ola[r];
        out[(size_t)qa * (NUM_HEADS * HEAD_DIM) + hh * 64 + l31]      = o0a[r] * inva;
        out[(size_t)qa * (NUM_HEADS * HEAD_DIM) + hh * 64 + 32 + l31] = o1a[r] * inva;
        const int qb = qa + 32;
        const float invb = 1.0f / olb[r];
        out[(size_t)qb * (NUM_HEADS * HEAD_DIM) + hh * 64 + l31]      = o0b[r] * invb;
        out[(size_t)qb * (NUM_HEADS * HEAD_DIM) + hh * 64 + 32 + l31] = o1b[r] * invb;
    }
}

extern "C" void kernel_launch(void* const* d_in, const int* in_sizes, int n_in,
                              void* d_out, int out_size, void* d_ws, size_t ws_size,
                              hipStream_t stream) {
    const float* h  = (const float*)d_in[0];
    const float* Wq = (const float*)d_in[1];
    const float* Wk = (const float*)d_in[2];
    const float* Wv = (const float*)d_in[3];
    const float* bq = (const float*)d_in[4];
    const float* bk = (const float*)d_in[5];
    const float* bv = (const float*)d_in[6];
    float* out = (float*)d_out;

    char* ws = (char*)d_ws;
    const size_t MB = 1024 * 1024;
    bf16* hb = (bf16*)(ws);
    bf16* Wt = (bf16*)(ws + 8 * MB);
    bf16* Qb = (bf16*)(ws + 14 * MB);
    bf16* Kb = (bf16*)(ws + 22 * MB);
    bf16* Vt = (bf16*)(ws + 30 * MB);

    mha_conv_h<<<(SEQ * IN_DIM / 4) / 256, 256, 0, stream>>>(h, hb);
    mha_conv_wt<<<dim3(16, 16, 3), 256, 0, stream>>>(Wq, Wk, Wv, Wt);
    mha_qkv_gemm<<<dim3(SEQ / 128, (3 * IN_DIM) / 128), 256, 0, stream>>>(
        hb, Wt, bq, bk, bv, Qb, Kb, Vt);
    // 256 q-rows per block (4 waves x 64): (SEQ/256) * NUM_HEADS = 256 blocks.
    mha_attn<<<dim3((SEQ / 256) * NUM_HEADS), 256, 0, stream>>>(Qb, Kb, Vt, out);
}

// Round 11
// 204.563 us; speedup vs baseline: 1.2592x; 1.2592x over previous
//
#include <hip/hip_runtime.h>
#include <hip/hip_bf16.h>

#define IN_DIM    1024
#define HEAD_DIM  64
#define NUM_HEADS 16
#define SEQ       4096

// 1/sqrt(64) * log2(e), folded into Q (fp32, pre-bf16-cast). Softmax computed
// with exp2 (v_exp_f32 IS 2^x) -> no per-element ln2 prescale mul in attn.
#define QSCALE 0.18033688011112042f

typedef __bf16 bf16;
typedef __attribute__((ext_vector_type(4))) __bf16 bf16x4;
typedef __attribute__((ext_vector_type(8))) __bf16 bf16x8;
typedef __attribute__((ext_vector_type(4))) float floatx4;
typedef __attribute__((ext_vector_type(16))) float floatx16;
typedef __attribute__((ext_vector_type(4))) unsigned uint32x4;

__device__ __forceinline__ void async16(bf16* lds, const bf16* g) {
    __builtin_amdgcn_global_load_lds(
        (const __attribute__((address_space(1))) unsigned int*)g,
        (__attribute__((address_space(3))) unsigned int*)lds, 16, 0, 0);
}

__device__ __forceinline__ unsigned cvtpk_bf16(float lo, float hi) {
    unsigned r;
    asm("v_cvt_pk_bf16_f32 %0, %1, %2" : "=v"(r) : "v"(lo), "v"(hi));
    return r;
}

// v_permlane32_swap_b32 vdst, vsrc (CDNA4): vdst[32:63] <-> vsrc[0:31]
// (arg order verified R2; single PACK chain per iter = verified v4 schedule)
__device__ __forceinline__ void permswap(unsigned& a, unsigned& b) {
    asm("v_permlane32_swap_b32 %0, %1" : "+v"(a), "+v"(b));
}

// ---------------------------------------------------------------------------
// ws layout: hb @0 (8MB) | Wt @8MB (6MB, n-major) | Qb @14MB | Kb @22MB | Vt @30MB
// ---------------------------------------------------------------------------

__global__ void mha_conv_h(const float* __restrict__ h, bf16* __restrict__ hb) {
    int i = blockIdx.x * blockDim.x + threadIdx.x;
    float4 v = ((const float4*)h)[i];
    bf16x4 r;
    r[0] = (bf16)v.x; r[1] = (bf16)v.y; r[2] = (bf16)v.z; r[3] = (bf16)v.w;
    ((bf16x4*)hb)[i] = r;
}

__global__ void mha_conv_wt(const float* __restrict__ Wq, const float* __restrict__ Wk,
                            const float* __restrict__ Wv, bf16* __restrict__ Wt) {
    __shared__ bf16 tile[64][65];
    const int mat = blockIdx.z;
    const float* W = (mat == 0) ? Wq : (mat == 1) ? Wk : Wv;
    const int k0 = blockIdx.y * 64, n0 = blockIdx.x * 64;
    const int tn = threadIdx.x & 63, tq = threadIdx.x >> 6;
#pragma unroll
    for (int i = 0; i < 16; ++i) {
        int kk = tq + i * 4;
        tile[kk][tn] = (bf16)W[(size_t)(k0 + kk) * 1024 + n0 + tn];
    }
    __syncthreads();
#pragma unroll
    for (int i = 0; i < 16; ++i) {
        int nn = tq + i * 4;
        Wt[((size_t)mat << 20) + (size_t)(n0 + nn) * 1024 + k0 + tn] = tile[tn][nn];
    }
}

// ---------------------------------------------------------------------------
// QKV GEMM v8: 128x128 tile, BK=64 (was 32).  R10 diagnosis: at K=1024 the
// m97 loop is BARRIER-DRAIN-bound -- each of 32 k-iters pays a vmcnt(0) L2
// round-trip (~300+ cyc) against only 78 cyc of MFMA.  BK=64 doubles compute
// per drain (32 MFMA) and halves drain events (16 iters).  LDS 32KB, still
// VGPR-limited ~3 blocks/CU.  Staging chunk math is R7's stage_half (passed
// correctness there) re-derived for 256 threads: tile = 128 rows x 8 chunks
// of 16B = 1024 chunks; thread stages ci = tid + 256j (j=0..3); row = ci>>3,
// src chunk gc = (ci&7)^(row&7) -- invariant across j since 32j = 0 mod 8.
// Frag reads: global k = kk*32 + quad*8 + e -> LDS chunk (kk*4+quad)^(l16&7).
// Epilogue byte-identical to the verified R0 version.
// ---------------------------------------------------------------------------
__launch_bounds__(256)
__global__ void mha_qkv_gemm(const bf16* __restrict__ hb, const bf16* __restrict__ Wt,
                             const float* __restrict__ bq, const float* __restrict__ bk,
                             const float* __restrict__ bv,
                             bf16* __restrict__ Qb, bf16* __restrict__ Kb,
                             bf16* __restrict__ Vt) {
    __shared__ __align__(16) bf16 As[128 * 64];   // 16 KB
    __shared__ __align__(16) bf16 Bs[128 * 64];   // 16 KB

    const int tid  = threadIdx.x;
    const int lane = tid & 63;
    const int wave = tid >> 6;
    const int l16  = lane & 15;
    const int quad = lane >> 4;
    const int wm   = wave & 1;
    const int wn   = wave >> 1;

    const int m0  = blockIdx.x * 128;
    const int n0  = blockIdx.y * 128;
    const int mat = n0 >> 10;
    const int nc0 = n0 & 1023;

    const bf16* Ap = hb + (size_t)m0 * 1024;
    const bf16* Bp = Wt + ((size_t)mat << 20) + (size_t)nc0 * 1024;

    const int srow = tid >> 3;                    // rows 0..31 (j adds 32)
    const int gc   = (tid & 7) ^ (srow & 7);      // same for all j
    const int swz  = l16 & 7;

    floatx4 acc[4][4] = {};

    for (int k0 = 0; k0 < IN_DIM; k0 += 64) {
#pragma unroll
        for (int j = 0; j < 4; ++j) {
            const int row = srow + 32 * j;
            async16(As + wave * 512 + j * 2048, Ap + (size_t)row * 1024 + k0 + gc * 8);
            async16(Bs + wave * 512 + j * 2048, Bp + (size_t)row * 1024 + k0 + gc * 8);
        }
        __syncthreads();

        bf16x8 af[4][2], bfr[4][2];
#pragma unroll
        for (int mt = 0; mt < 4; ++mt)
#pragma unroll
            for (int kk = 0; kk < 2; ++kk)
                af[mt][kk] = *(const bf16x8*)(As + (size_t)(wm * 64 + mt * 16 + l16) * 64
                                              + (((kk * 4 + quad) ^ swz) * 8));
#pragma unroll
        for (int nt = 0; nt < 4; ++nt)
#pragma unroll
            for (int kk = 0; kk < 2; ++kk)
                bfr[nt][kk] = *(const bf16x8*)(Bs + (size_t)(wn * 64 + nt * 16 + l16) * 64
                                               + (((kk * 4 + quad) ^ swz) * 8));
#pragma unroll
        for (int kk = 0; kk < 2; ++kk)
#pragma unroll
            for (int mt = 0; mt < 4; ++mt)
#pragma unroll
                for (int nt = 0; nt < 4; ++nt)
                    acc[mt][nt] = __builtin_amdgcn_mfma_f32_16x16x32_bf16(
                        af[mt][kk], bfr[nt][kk], acc[mt][nt], 0, 0, 0);
        __syncthreads();
    }

    const float* bias = (mat == 0) ? bq : (mat == 1) ? bk : bv;
#pragma unroll
    for (int nt = 0; nt < 4; ++nt) {
        int nc = nc0 + wn * 64 + nt * 16 + l16;
        float bb = bias[nc];
        int head = nc >> 6, d = nc & 63;
#pragma unroll
        for (int mt = 0; mt < 4; ++mt)
#pragma unroll
            for (int r = 0; r < 4; ++r) {
                int srow_o = m0 + wm * 64 + mt * 16 + quad * 4 + r;
                float v = acc[mt][nt][r] + bb;
                if (mat == 0)
                    Qb[((size_t)head * SEQ + srow_o) * HEAD_DIM + d] = (bf16)(v * QSCALE);
                else if (mat == 1)
                    Kb[((size_t)head * SEQ + srow_o) * HEAD_DIM + d] = (bf16)v;
                else
                    Vt[((size_t)head * HEAD_DIM + d) * SEQ + srow_o] = (bf16)v;
            }
    }
}

// ---------------------------------------------------------------------------
// Attention (R4-EXACT, verified 94-99us across R4/R6/R7): 8 waves x 32
// q-rows (256 q/block, 1 block/CU), 32x32x16 MFMA, in-register P transpose,
// counted-vmcnt 3-buffer pipeline, XCD-head swizzle (K/V L2-resident).
// R5 (2x occupancy), R10 (4wx64q) both failed to beat it -- the structure's
// ~3540 cyc/iter is its plateau.  Frozen this session.
// ---------------------------------------------------------------------------
__launch_bounds__(512)
__global__ void mha_attn(const bf16* __restrict__ Qb, const bf16* __restrict__ Kb,
                         const bf16* __restrict__ Vt, float* __restrict__ out) {
    __shared__ __align__(16) bf16 Ks[3][64 * 64];       // 24 KB
    __shared__ __align__(16) bf16 Vs[3][64 * 64];       // 24 KB (d-major V^T)

    const int lane = threadIdx.x & 63;
    const int wave = threadIdx.x >> 6;
    const int l31  = lane & 31;
    const int hi   = lane >> 5;

    // XCD-head swizzle: 256 blocks; XCD k (= bid%8) gets heads {2k, 2k+1}
    const int bid = blockIdx.x;
    const int hh  = 2 * (bid & 7) + ((bid >> 3) & 1);
    const int qx  = bid >> 4;
    const int q0  = qx * 256 + wave * 32;

    const bf16* Qh = Qb + (size_t)hh * SEQ * HEAD_DIM;
    const bf16* Kh = Kb + (size_t)hh * SEQ * HEAD_DIM;
    const bf16* Vh = Vt + (size_t)hh * HEAD_DIM * SEQ;

    const int sg   = wave * 64 + lane;           // 0..511
    const int srow = sg >> 3;                    // 0..63
    const int sgc  = (sg & 7) ^ (srow & 7);

    bf16x8 qf[4];
#pragma unroll
    for (int ks = 0; ks < 4; ++ks)
        qf[ks] = *(const bf16x8*)(Qh + (size_t)(q0 + l31) * HEAD_DIM + ks * 16 + hi * 8);

    bf16x8 vone;
#pragma unroll
    for (int i = 0; i < 8; ++i) vone[i] = (bf16)1.0f;

    floatx16 o0 = {}, o1 = {}, ol = {};
    const int swz = l31 & 7;

    async16(&Ks[0][wave * 512], Kh + (size_t)srow * HEAD_DIM + sgc * 8);
    async16(&Vs[0][wave * 512], Vh + (size_t)srow * SEQ + 0 + sgc * 8);
    async16(&Ks[1][wave * 512], Kh + (size_t)(64 + srow) * HEAD_DIM + sgc * 8);
    async16(&Vs[1][wave * 512], Vh + (size_t)srow * SEQ + 64 + sgc * 8);
    asm volatile("s_waitcnt vmcnt(0)" ::: "memory");
    __builtin_amdgcn_s_barrier();

    int cur = 0;
    for (int t = 0; t < SEQ / 64; ++t) {
        int pre = cur + 2; if (pre >= 3) pre -= 3;
        if (t + 2 < SEQ / 64) {
            const int tg = (t + 2) * 64;
            async16(&Ks[pre][wave * 512], Kh + (size_t)(tg + srow) * HEAD_DIM + sgc * 8);
            async16(&Vs[pre][wave * 512], Vh + (size_t)srow * SEQ + tg + sgc * 8);
        }
        if (t < SEQ / 64 - 2)       asm volatile("s_waitcnt vmcnt(4)" ::: "memory");
        else if (t == SEQ / 64 - 2) asm volatile("s_waitcnt vmcnt(2)" ::: "memory");
        else                        asm volatile("s_waitcnt vmcnt(0)" ::: "memory");
        __builtin_amdgcn_s_barrier();
        asm volatile("" ::: "memory");

        bf16x8 kf[2][4];
#pragma unroll
        for (int tt = 0; tt < 2; ++tt)
#pragma unroll
            for (int ks = 0; ks < 4; ++ks)
                kf[tt][ks] = *(const bf16x8*)(&Ks[cur][(tt * 32 + l31) * 64
                                              + (((ks * 2 + hi) ^ swz) * 8)]);

        floatx16 s0 = {}, s1 = {};
#pragma unroll
        for (int ks = 0; ks < 4; ++ks)
            s0 = __builtin_amdgcn_mfma_f32_32x32x16_bf16(kf[0][ks], qf[ks], s0, 0, 0, 0);
#pragma unroll
        for (int ks = 0; ks < 4; ++ks)
            s1 = __builtin_amdgcn_mfma_f32_32x32x16_bf16(kf[1][ks], qf[ks], s1, 0, 0, 0);

        bf16x8 vf[2][4];
#pragma unroll
        for (int dt = 0; dt < 2; ++dt)
#pragma unroll
            for (int sl = 0; sl < 4; ++sl)
                vf[dt][sl] = *(const bf16x8*)(&Vs[cur][(dt * 32 + l31) * 64
                                              + (((sl * 2 + hi) ^ swz) * 8)]);

        bf16x8 pa[4];
#pragma unroll
        for (int sl = 0; sl < 4; ++sl) {
            const floatx16 sv = (sl < 2) ? s0 : s1;
            const int rb = 8 * (sl & 1);
            float p0 = __builtin_amdgcn_exp2f(sv[rb + 0]);
            float p1 = __builtin_amdgcn_exp2f(sv[rb + 1]);
            float p2 = __builtin_amdgcn_exp2f(sv[rb + 2]);
            float p3 = __builtin_amdgcn_exp2f(sv[rb + 3]);
            float p4 = __builtin_amdgcn_exp2f(sv[rb + 4]);
            float p5 = __builtin_amdgcn_exp2f(sv[rb + 5]);
            float p6 = __builtin_amdgcn_exp2f(sv[rb + 6]);
            float p7 = __builtin_amdgcn_exp2f(sv[rb + 7]);
            unsigned u0 = cvtpk_bf16(p0, p1);
            unsigned u1 = cvtpk_bf16(p2, p3);
            unsigned u2 = cvtpk_bf16(p4, p5);
            unsigned u3 = cvtpk_bf16(p6, p7);
            permswap(u0, u2);
            permswap(u1, u3);
            uint32x4 w;
            w[0] = u0; w[1] = u1; w[2] = u2; w[3] = u3;
            pa[sl] = __builtin_bit_cast(bf16x8, w);
        }

#pragma unroll
        for (int sl = 0; sl < 4; ++sl) {
            o0 = __builtin_amdgcn_mfma_f32_32x32x16_bf16(pa[sl], vf[0][sl], o0, 0, 0, 0);
            o1 = __builtin_amdgcn_mfma_f32_32x32x16_bf16(pa[sl], vf[1][sl], o1, 0, 0, 0);
            ol = __builtin_amdgcn_mfma_f32_32x32x16_bf16(pa[sl], vone, ol, 0, 0, 0);
        }

        asm volatile("" ::: "memory");
        __builtin_amdgcn_s_barrier();      // reads of buf[cur] done before restage
        cur = cur + 1; if (cur == 3) cur = 0;
    }

#pragma unroll
    for (int r = 0; r < 16; ++r) {
        const int q = q0 + (r & 3) + 8 * (r >> 2) + 4 * hi;
        const float inv = 1.0f / ol[r];
        out[(size_t)q * (NUM_HEADS * HEAD_DIM) + hh * 64 + l31]      = o0[r] * inv;
        out[(size_t)q * (NUM_HEADS * HEAD_DIM) + hh * 64 + 32 + l31] = o1[r] * inv;
    }
}

extern "C" void kernel_launch(void* const* d_in, const int* in_sizes, int n_in,
                              void* d_out, int out_size, void* d_ws, size_t ws_size,
                              hipStream_t stream) {
    const float* h  = (const float*)d_in[0];
    const float* Wq = (const float*)d_in[1];
    const float* Wk = (const float*)d_in[2];
    const float* Wv = (const float*)d_in[3];
    const float* bq = (const float*)d_in[4];
    const float* bk = (const float*)d_in[5];
    const float* bv = (const float*)d_in[6];
    float* out = (float*)d_out;

    char* ws = (char*)d_ws;
    const size_t MB = 1024 * 1024;
    bf16* hb = (bf16*)(ws);
    bf16* Wt = (bf16*)(ws + 8 * MB);
    bf16* Qb = (bf16*)(ws + 14 * MB);
    bf16* Kb = (bf16*)(ws + 22 * MB);
    bf16* Vt = (bf16*)(ws + 30 * MB);

    mha_conv_h<<<(SEQ * IN_DIM / 4) / 256, 256, 0, stream>>>(h, hb);
    mha_conv_wt<<<dim3(16, 16, 3), 256, 0, stream>>>(Wq, Wk, Wv, Wt);
    mha_qkv_gemm<<<dim3(SEQ / 128, (3 * IN_DIM) / 128), 256, 0, stream>>>(
        hb, Wt, bq, bk, bv, Qb, Kb, Vt);
    mha_attn<<<dim3((SEQ / 256) * NUM_HEADS), 512, 0, stream>>>(Qb, Kb, Vt, out);
}